// Round 10
// baseline (362.020 us; speedup 1.0000x reference)
//
#include <hip/hip_runtime.h>

// conv3d(8ci->8co, 3x3x3, same) + relu/leaky/gelu/sigmoid + bias, via bf16 MFMA.
//
// GEMM view, DUAL-D (R12): m = w-pos (16), n = co + 8*s (s = output slice d+s),
// k = tap'*8+ci, tap' over kd' in [0,4) x (kh,kw) = 36 taps = 9 K=32 steps.
// LDS [slice][h][w][ci] bf16, 6-slot ring, slice s -> slot (s+1)%6.
//
// History: R9 117us | R10 d-split x4 235us (cache thrash) | R11 T14+pin 155us |
// R12 dual-d 114us (BEST) | R13 cross-barrier prefetch 150us (spills) |
// R14 weak-barrier reorder 146us (regression, traffic tell again).
// Scheduling verdict: R12's compiler schedule is not beatable at source level
// for this structure (guide Common-mistake #5, confirmed 3x). All manual
// waitcnt/barrier/prefetch experiments reverted.
//
// R12 residual profile: Mfma 6.5 / VALU 29 / HBM 32% / conflicts ~0 --
// nothing busy, and Occupancy 37% is GRID-CAPPED: 1024 blocks = 4 blocks/CU
// = 16/32 waves. Latency-bound for lack of TLP.
//
// R15 (this): w-split 64->32 (wb 2->4, grid 2048, lowest dispatch bits so
// adjacent blocks stay L2-adjacent -- NOT the d-split that thrashed in R10).
// ROWPTS 34, SLICEB 3264, ring 19.6 KB -> 8 blocks/CU = 32 waves/CU;
// __launch_bounds__(256,8) (VGPR cap 64 = measured usage). Iteration
// structure byte-for-byte R12: fused stage, plain __syncthreads.

#define CIN 8
#define COUT 8
#define DDIM 32
#define HDIM 128
#define WDIM 128
#define HWSZ (HDIM * WDIM)           // 16384
#define CISTR (DDIM * HWSZ)          // x ci stride in floats

#define WTILE 32                     // output w per block
#define ROWPTS 34                    // w = -1..32 (32-wide tile + halo)
#define ROWB   (ROWPTS * 16)         // 544 B
#define SROWS  6                     // h = -1..4 (4-high tile + halo)
#define SLICEPTS (SROWS * ROWPTS)    // 204 points (<= 256: 1 point/thread)
#define SLICEB (SROWS * ROWB)        // 3264 B
#define NSLOT 6
#define LDSB (NSLOT * SLICEB)        // 19584 B -> 8 blocks/CU (156.7 of 160 KB)
#define ND 16                        // output d per block (dsplit = 2); step 2

typedef short short8 __attribute__((ext_vector_type(8)));
typedef float floatx4 __attribute__((ext_vector_type(4)));

static __device__ __forceinline__ unsigned f2bf(float f) {
    unsigned u = __builtin_bit_cast(unsigned, f);
    return (u + 0x7FFFu + ((u >> 16) & 1u)) >> 16;   // RTN-even bf16
}

static __device__ __forceinline__ float act(float v, float bco) {
    float y = fmaxf(v, 0.f);                         // relu (leaky is identity after relu)
    float t = 0.7978845608028654f * (y + 0.044715f * y * y * y);
    float e = __builtin_amdgcn_exp2f(2.8853900817779268f * t);       // e^{2t}
    float g = y - y * __builtin_amdgcn_rcpf(1.f + e);                // tanh-gelu
    float s = __builtin_amdgcn_rcpf(1.f + __builtin_amdgcn_exp2f(-1.4426950408889634f * g));
    return s + bco;                                  // sigmoid + channel bias
}

// Block: 256 threads = 4 waves; wave w handles output h-row (h0+w), 2 w-chunks of 16.
// Grid: 4 wb * 32 hb * 8 b * 2 dsplit = 2048 blocks; 8 dual-d iterations per block.
__global__ __launch_bounds__(256, 8) void conv3d_mfma_kernel(
    const float* __restrict__ x,
    const float* __restrict__ wgt,
    const float* __restrict__ bias,
    float* __restrict__ out)
{
    __shared__ __align__(16) char lds[LDSB];

    const int tid  = threadIdx.x;
    const int lane = tid & 63;
    const int wid  = tid >> 6;        // wave id = local h row 0..3
    const int m    = lane & 15;       // A-row (w pos); also n = co + 8*ds for B, C/D
    const int g    = lane >> 4;       // k-group 0..3
    const int co   = m & 7;           // output channel
    const int ds   = m >> 3;          // output d offset s in {0,1}

    int bx = blockIdx.x;
    const int wb = bx & 3;   bx >>= 2;
    const int hb = bx & 31;  bx >>= 5;
    const int b  = bx & 7;   bx >>= 3;
    const int d0 = bx * ND;           // d split: d0 in {0,16}
    const int h0 = hb * 4;
    const int W0 = wb * WTILE;
    const int dlim = d0 + ND;         // last slice index ever needed

    const float* xb = x + (size_t)b * CIN * CISTR;

    // ---- B fragments (weights), 9 k-steps over 36 taps', n = co+8*ds ----
    short8 bw[9];
    unsigned aoff[9];                 // per-lane A byte offset: kd'*SLICEB + spatial
    #pragma unroll
    for (int t = 0; t < 9; ++t) {
        const int tap = 4 * t + g;    // 0..35, no pad
        const int kd = tap / 9, r = tap % 9;
        const int kh = r / 3, kw = r % 3;
        const int kds = kd - ds;
        const bool wok = (kds >= 0) & (kds < 3);
        #pragma unroll
        for (int j = 0; j < 8; ++j) {
            float v = wok ? wgt[(co * CIN + j) * 27 + kds * 9 + kh * 3 + kw] : 0.f;
            bw[t][j] = (short)f2bf(v);
        }
        aoff[t] = (unsigned)(kd * SLICEB + (kh + wid) * ROWB + (m + kw) * 16);
    }
    const float bco = bias[co];

    // ---- staging geometry, d-invariant: 1 point per thread (p = tid < 204) ----
    const int p  = tid;
    const int hh = p / ROWPTS, ww = p - hh * ROWPTS;
    const int hg = h0 + hh - 1, wg = W0 + ww - 1;
    const bool okhw = (p < SLICEPTS) & ((unsigned)hg < HDIM) & ((unsigned)wg < WDIM);
    const int  soff = hg * WDIM + wg;       // junk when !okhw -- never dereferenced
    const int  ldso = p * 16;
    const bool wr0  = p < SLICEPTS;

    // ---- staging: slice dg -> slot (dg+1)%6, zero-fill outside the volume ----
    // Fused load+pack+write (R12 style): compiler overlaps it with MFMAs itself.
    auto stage = [&](int dg) {
        char* sb = lds + ((dg + 1) % NSLOT) * SLICEB;
        const float* xs = xb + (size_t)dg * HWSZ;
        const bool din = (unsigned)dg < DDIM;
        if (wr0) {
            const bool ok = okhw & din;
            const float* src = xs + soff;
            unsigned q[4];
            #pragma unroll
            for (int c = 0; c < 4; ++c) {
                float v0 = ok ? src[(2 * c    ) * CISTR] : 0.f;   // coalesced per-ci loads
                float v1 = ok ? src[(2 * c + 1) * CISTR] : 0.f;
                q[c] = f2bf(v0) | (f2bf(v1) << 16);
            }
            *(int4*)(sb + ldso) = make_int4(q[0], q[1], q[2], q[3]);
        }
    };

    // ---- prologue: slices d0-1 .. d0+2 ----
    stage(d0 - 1); stage(d0); stage(d0 + 1); stage(d0 + 2);
    __syncthreads();

    // slot of slice s is (s+1)%6; iter d reads slices d-1..d+2 -> slots (d..d+3)%6.
    unsigned sdB = (unsigned)(d0 % NSLOT) * SLICEB;

    for (int d = d0; d < dlim; d += 2) {
        // stage slices d+3,d+4 -> slots (d+4)%6,(d+5)%6; reads use (d..d+3)%6.
        if (d + 4 <= dlim) { stage(d + 3); stage(d + 4); }

        floatx4 acc0 = {0,0,0,0}, acc1 = {0,0,0,0};
        #pragma unroll
        for (int t = 0; t < 9; ++t) {
            unsigned off = sdB + aoff[t];
            off = (off >= (unsigned)LDSB) ? off - (unsigned)LDSB : off;
            const char* ap = lds + off;
            short8 a0 = __builtin_bit_cast(short8, *(const int4*)(ap      ));
            short8 a1 = __builtin_bit_cast(short8, *(const int4*)(ap + 256));
            acc0 = __builtin_amdgcn_mfma_f32_16x16x32_bf16(a0, bw[t], acc0, 0, 0, 0);
            acc1 = __builtin_amdgcn_mfma_f32_16x16x32_bf16(a1, bw[t], acc1, 0, 0, 0);
        }

        // C/D: col n = co+8*ds, rows g*4+reg -> 4 consecutive w; chunks at +0,+16.
        {
            float* op = out + ((size_t)(b * COUT + co) * DDIM + (d + ds)) * HWSZ
                            + (h0 + wid) * WDIM + W0 + g * 4;
            *(float4*)(op)      = make_float4(act(acc0[0],bco), act(acc0[1],bco), act(acc0[2],bco), act(acc0[3],bco));
            *(float4*)(op + 16) = make_float4(act(acc1[0],bco), act(acc1[1],bco), act(acc1[2],bco), act(acc1[3],bco));
        }

        __syncthreads();
        sdB += 2 * SLICEB;
        if (sdB >= (unsigned)LDSB) sdB -= (unsigned)LDSB;
    }
}

extern "C" void kernel_launch(void* const* d_in, const int* in_sizes, int n_in,
                              void* d_out, int out_size, void* d_ws, size_t ws_size,
                              hipStream_t stream) {
    const float* x    = (const float*)d_in[0];
    const float* wgt  = (const float*)d_in[1];
    const float* bias = (const float*)d_in[2];
    float* out = (float*)d_out;

    dim3 grid(4 * 32 * 8 * 2);   // wb * hb * b * dsplit = 2048
    dim3 block(256);
    conv3d_mfma_kernel<<<grid, block, 0, stream>>>(x, wgt, bias, out);
}

// Round 11
// 271.219 us; speedup vs baseline: 1.3348x; 1.3348x over previous
//
#include <hip/hip_runtime.h>

// conv3d(8ci->8co, 3x3x3, same) + relu/leaky/gelu/sigmoid + bias, via bf16 MFMA.
//
// GEMM view, DUAL-D (R12): m = w-pos (16), n = co + 8*s (s = output slice d+s),
// k = tap'*8+ci, tap' over kd' in [0,4) x (kh,kw) = 36 taps = 9 K=32 steps.
// LDS [slice][h][w][ci] bf16, 6-slot ring, slice s -> slot (s+1)%6.
//
// History: R9 117 | R10 d-split 235 (thrash) | R11 T14+pin 155 | R12 dual-d
// 114 (BEST) | R13 xbar-prefetch 150 (spills) | R14 weak-barrier 146 |
// R15 w-split32 198: occupancy 84% and BW 3.15 TB/s (occupancy DOES raise
// achieved BW) but FETCH 360/WRITE 249 MB -- 128B output segments hit a
// ~256B HBM write granularity => RMW (WRITE 1.9x, FETCH +RMW reads); and
// wb in low dispatch bits put w-adjacent blocks on different XCDs (bid%8),
// duplicating x lines across L2s. RULES: w-tile >= 64; traffic >> scheduling.
//
// R16 (this): EXACT R12 kernel + T1 XCD swizzle only.
// bx = (bid%8)*128 + bid/8 : each XCD gets 128 consecutive logical blocks =
// all 64 (wb,hb) tiles of 2 (b,dsplit) planes; 128 = XCD concurrent capacity
// (32 CU x 4 blk) so the chunk co-resides and walks d in lockstep. Live x
// window ~3.1 MB < 4 MB XCD L2 -> h/w-halo re-reads become local L2 hits;
// HBM reads x ~once. nwg=1024 divisible by 8 -> bijective.

#define CIN 8
#define COUT 8
#define DDIM 32
#define HDIM 128
#define WDIM 128
#define HWSZ (HDIM * WDIM)           // 16384
#define CISTR (DDIM * HWSZ)          // x ci stride in floats

#define ROWPTS 66                    // w = -1..64 (64-wide tile + halo)
#define ROWB   (ROWPTS * 16)         // 1056 B
#define SROWS  6                     // h = -1..4 (4-high tile + halo)
#define SLICEPTS (SROWS * ROWPTS)    // 396 points
#define SLICEB (SROWS * ROWB)        // 6336 B
#define NSLOT 6
#define LDSB (NSLOT * SLICEB)        // 38016 B -> 4 blocks/CU
#define ND 16                        // output d per block (dsplit = 2); step 2

typedef short short8 __attribute__((ext_vector_type(8)));
typedef float floatx4 __attribute__((ext_vector_type(4)));

static __device__ __forceinline__ unsigned f2bf(float f) {
    unsigned u = __builtin_bit_cast(unsigned, f);
    return (u + 0x7FFFu + ((u >> 16) & 1u)) >> 16;   // RTN-even bf16
}

static __device__ __forceinline__ float act(float v, float bco) {
    float y = fmaxf(v, 0.f);                         // relu (leaky is identity after relu)
    float t = 0.7978845608028654f * (y + 0.044715f * y * y * y);
    float e = __builtin_amdgcn_exp2f(2.8853900817779268f * t);       // e^{2t}
    float g = y - y * __builtin_amdgcn_rcpf(1.f + e);                // tanh-gelu
    float s = __builtin_amdgcn_rcpf(1.f + __builtin_amdgcn_exp2f(-1.4426950408889634f * g));
    return s + bco;                                  // sigmoid + channel bias
}

// Block: 256 threads = 4 waves; wave w handles output h-row (h0+w), 4 w-chunks of 16.
// Grid: 2 wb * 32 hb * 8 b * 2 dsplit = 1024 blocks; 8 dual-d iterations per block.
__global__ __launch_bounds__(256, 4) void conv3d_mfma_kernel(
    const float* __restrict__ x,
    const float* __restrict__ wgt,
    const float* __restrict__ bias,
    float* __restrict__ out)
{
    __shared__ __align__(16) char lds[LDSB];

    const int tid  = threadIdx.x;
    const int lane = tid & 63;
    const int wid  = tid >> 6;        // wave id = local h row 0..3
    const int m    = lane & 15;       // A-row (w pos); also n = co + 8*ds for B, C/D
    const int g    = lane >> 4;       // k-group 0..3
    const int co   = m & 7;           // output channel
    const int ds   = m >> 3;          // output d offset s in {0,1}

    // T1 XCD swizzle: HW assigns XCD by blockIdx%8 (round-robin); give XCD k
    // the logical blocks [k*128, (k+1)*128) of R12's linear order.
    const int bid = blockIdx.x;
    int bx = (bid & 7) * 128 + (bid >> 3);

    const int wb = bx & 1;   bx >>= 1;
    const int hb = bx & 31;  bx >>= 5;
    const int b  = bx & 7;   bx >>= 3;
    const int d0 = bx * ND;           // d split: d0 in {0,16}
    const int h0 = hb * 4;
    const int W0 = wb * 64;
    const int dlim = d0 + ND;         // last slice index ever needed

    const float* xb = x + (size_t)b * CIN * CISTR;

    // ---- B fragments (weights), 9 k-steps over 36 taps', n = co+8*ds ----
    short8 bw[9];
    unsigned aoff[9];                 // per-lane A byte offset: kd'*SLICEB + spatial
    #pragma unroll
    for (int t = 0; t < 9; ++t) {
        const int tap = 4 * t + g;    // 0..35, no pad
        const int kd = tap / 9, r = tap % 9;
        const int kh = r / 3, kw = r % 3;
        const int kds = kd - ds;
        const bool wok = (kds >= 0) & (kds < 3);
        #pragma unroll
        for (int j = 0; j < 8; ++j) {
            float v = wok ? wgt[(co * CIN + j) * 27 + kds * 9 + kh * 3 + kw] : 0.f;
            bw[t][j] = (short)f2bf(v);
        }
        aoff[t] = (unsigned)(kd * SLICEB + (kh + wid) * ROWB + (m + kw) * 16);
    }
    const float bco = bias[co];

    // ---- staging geometry, d-invariant: 2 points per thread (p = tid, tid+256) ----
    int  soff[2];
    bool okhw[2];
    int  ldso[2];
    #pragma unroll
    for (int i = 0; i < 2; ++i) {
        const int p  = tid + 256 * i;
        const int hh = p / ROWPTS, ww = p - hh * ROWPTS;
        const int hg = h0 + hh - 1, wg = W0 + ww - 1;
        okhw[i] = (p < SLICEPTS) & ((unsigned)hg < HDIM) & ((unsigned)wg < WDIM);
        soff[i] = hg * WDIM + wg;          // junk when !okhw -- never dereferenced
        ldso[i] = p * 16;
    }

    // ---- staging: slice dg -> slot (dg+1)%6, zero-fill outside the volume ----
    // Fused load+pack+write (R12 style): compiler overlaps it with MFMAs itself.
    auto stage = [&](int dg) {
        char* sb = lds + ((dg + 1) % NSLOT) * SLICEB;
        const float* xs = xb + (size_t)dg * HWSZ;
        const bool din = (unsigned)dg < DDIM;
        #pragma unroll
        for (int i = 0; i < 2; ++i) {
            const int p = tid + 256 * i;
            if (p < SLICEPTS) {
                const bool ok = okhw[i] & din;
                const float* src = xs + soff[i];
                unsigned q[4];
                #pragma unroll
                for (int c = 0; c < 4; ++c) {
                    float v0 = ok ? src[(2 * c    ) * CISTR] : 0.f;   // coalesced per-ci loads
                    float v1 = ok ? src[(2 * c + 1) * CISTR] : 0.f;
                    q[c] = f2bf(v0) | (f2bf(v1) << 16);
                }
                *(int4*)(sb + ldso[i]) = make_int4(q[0], q[1], q[2], q[3]);
            }
        }
    };

    // ---- prologue: slices d0-1 .. d0+2 ----
    stage(d0 - 1); stage(d0); stage(d0 + 1); stage(d0 + 2);
    __syncthreads();

    // slot of slice s is (s+1)%6; iter d reads slices d-1..d+2 -> slots (d..d+3)%6.
    unsigned sdB = (unsigned)(d0 % NSLOT) * SLICEB;

    for (int d = d0; d < dlim; d += 2) {
        // stage slices d+3,d+4 -> slots (d+4)%6,(d+5)%6; reads use (d..d+3)%6.
        if (d + 4 <= dlim) { stage(d + 3); stage(d + 4); }

        floatx4 acc0 = {0,0,0,0}, acc1 = {0,0,0,0}, acc2 = {0,0,0,0}, acc3 = {0,0,0,0};
        #pragma unroll
        for (int t = 0; t < 9; ++t) {
            unsigned off = sdB + aoff[t];
            off = (off >= (unsigned)LDSB) ? off - (unsigned)LDSB : off;
            const char* ap = lds + off;
            short8 a0 = __builtin_bit_cast(short8, *(const int4*)(ap      ));
            short8 a1 = __builtin_bit_cast(short8, *(const int4*)(ap + 256));
            short8 a2 = __builtin_bit_cast(short8, *(const int4*)(ap + 512));
            short8 a3 = __builtin_bit_cast(short8, *(const int4*)(ap + 768));
            acc0 = __builtin_amdgcn_mfma_f32_16x16x32_bf16(a0, bw[t], acc0, 0, 0, 0);
            acc1 = __builtin_amdgcn_mfma_f32_16x16x32_bf16(a1, bw[t], acc1, 0, 0, 0);
            acc2 = __builtin_amdgcn_mfma_f32_16x16x32_bf16(a2, bw[t], acc2, 0, 0, 0);
            acc3 = __builtin_amdgcn_mfma_f32_16x16x32_bf16(a3, bw[t], acc3, 0, 0, 0);
        }

        // C/D: col n = co+8*ds, rows = g*4+reg -> 4 consecutive w. ALL 64 lanes
        // store; per (co,ds,h): 4 g-lanes fill a 256B segment (full HBM sector).
        {
            float* op = out + ((size_t)(b * COUT + co) * DDIM + (d + ds)) * HWSZ
                            + (h0 + wid) * WDIM + W0 + g * 4;
            *(float4*)(op)      = make_float4(act(acc0[0],bco), act(acc0[1],bco), act(acc0[2],bco), act(acc0[3],bco));
            *(float4*)(op + 16) = make_float4(act(acc1[0],bco), act(acc1[1],bco), act(acc1[2],bco), act(acc1[3],bco));
            *(float4*)(op + 32) = make_float4(act(acc2[0],bco), act(acc2[1],bco), act(acc2[2],bco), act(acc2[3],bco));
            *(float4*)(op + 48) = make_float4(act(acc3[0],bco), act(acc3[1],bco), act(acc3[2],bco), act(acc3[3],bco));
        }

        __syncthreads();
        sdB += 2 * SLICEB;
        if (sdB >= (unsigned)LDSB) sdB -= (unsigned)LDSB;
    }
}

extern "C" void kernel_launch(void* const* d_in, const int* in_sizes, int n_in,
                              void* d_out, int out_size, void* d_ws, size_t ws_size,
                              hipStream_t stream) {
    const float* x    = (const float*)d_in[0];
    const float* wgt  = (const float*)d_in[1];
    const float* bias = (const float*)d_in[2];
    float* out = (float*)d_out;

    dim3 grid(2 * 32 * 8 * 2);   // wb * hb * b * dsplit = 1024 logical blocks
    dim3 block(256);
    conv3d_mfma_kernel<<<grid, block, 0, stream>>>(x, wgt, bias, out);
}